// Round 1
// 579.263 us; speedup vs baseline: 1.1560x; 1.1560x over previous
//
#include <hip/hip_runtime.h>
#include <hip/hip_bf16.h>
#include <math.h>

#define BB 2
#define DIM 384
#define HID 384
#define HW 65536

typedef short s16x8 __attribute__((ext_vector_type(8)));
typedef __bf16 bf16x8 __attribute__((ext_vector_type(8)));
typedef float f32x4 __attribute__((ext_vector_type(4)));

__device__ inline short f2b(float f) {
    __hip_bfloat16 h = __float2bfloat16(f);
    return __builtin_bit_cast(short, h);
}
__device__ inline float b2f(short s) {
    return __bfloat162float(__builtin_bit_cast(__hip_bfloat16, s));
}

__device__ inline void gl_lds16(const short* g, short* l) {
    __builtin_amdgcn_global_load_lds(
        (const __attribute__((address_space(1))) unsigned int*)g,
        (__attribute__((address_space(3))) unsigned int*)l, 16, 0, 0);
}

// ---------------------------------------------------------------------------
// A: per-channel 8x8 circular-correlation taps from fft_filter
// ---------------------------------------------------------------------------
__global__ void k_precompute(const float* __restrict__ F, float* __restrict__ K) {
    int c = blockIdx.x;
    int t = threadIdx.x;
    int a = t >> 3, b = t & 7;
    const float ctab[8] = {1.f, 0.70710678118654752f, 0.f, -0.70710678118654752f,
                           -1.f, -0.70710678118654752f, 0.f, 0.70710678118654752f};
    const float* Fc = F + c * 40;
    float acc = 0.f;
#pragma unroll
    for (int up = 0; up < 8; ++up) {
#pragma unroll
        for (int vp = 0; vp < 5; ++vp) {
            float wv = (vp == 0 || vp == 4) ? 1.f : 2.f;
            int k = (a * up + b * vp) & 7;
            acc += wv * Fc[up * 5 + vp] * ctab[k];
        }
    }
    K[c * 64 + t] = acc * (1.f / 64.f);
}

__global__ void k_cvtw(const float* __restrict__ in, short* __restrict__ out, int n) {
    int i = blockIdx.x * 256 + threadIdx.x;
    if (i < n) out[i] = f2b(in[i]);
}

// ---------------------------------------------------------------------------
// x [b][c][hw] fp32  ->  Xt [b][hw][384] bf16
// XOR-swizzled LDS transpose: phys col = s ^ ((c>>3)<<3)  (2-way max, free)
// ---------------------------------------------------------------------------
__global__ __launch_bounds__(256) void k_cvtx(const float* __restrict__ X, short* __restrict__ Xt) {
    int hw0 = blockIdx.x * 64, c0 = blockIdx.y * 64, b = blockIdx.z;
    __shared__ __align__(16) short S[64 * 64];
    int t = threadIdx.x;
    const float* Xb = X + ((size_t)(b * DIM) << 16);
    short* Xtb = Xt + (size_t)b * HW * DIM;
#pragma unroll
    for (int p = 0; p < 2; ++p) {
        int row = p * 32 + (t >> 3), sb = t & 7;     // row = channel, sb = spatial octet
        const float* src = &Xb[((size_t)(c0 + row) << 16) + hw0 + sb * 8];
        float4 a = *(const float4*)src;
        float4 bq = *(const float4*)(src + 4);
        s16x8 v;
        v[0] = f2b(a.x);  v[1] = f2b(a.y);  v[2] = f2b(a.z);  v[3] = f2b(a.w);
        v[4] = f2b(bq.x); v[5] = f2b(bq.y); v[6] = f2b(bq.z); v[7] = f2b(bq.w);
        *(s16x8*)&S[row * 64 + ((sb ^ (row >> 3)) << 3)] = v;
    }
    __syncthreads();
#pragma unroll
    for (int p = 0; p < 2; ++p) {
        int row = p * 32 + (t >> 3), ch = t & 7;     // row = spatial, ch = channel octet
        s16x8 v;
#pragma unroll
        for (int j = 0; j < 8; ++j)
            v[j] = S[(ch * 8 + j) * 64 + (row ^ (ch << 3))];
        *(s16x8*)&Xtb[(size_t)(hw0 + row) * DIM + c0 + ch * 8] = v;
    }
}

// ---------------------------------------------------------------------------
// Pure GEMM1: E[b][c][patch][uv] bf16, patch-major output.
// n-tile (128) = 2 patches x 64 uv. B rows staged so row n <-> (u,v,pat).
// ---------------------------------------------------------------------------
__global__ __launch_bounds__(256) void k_gemm1_patch(const short* __restrict__ A,
                                                     const short* __restrict__ Bt,
                                                     short* __restrict__ E) {
    __shared__ __align__(16) short SH[17408];   // As[0..4095] | Bs[4096..8191]; Ep alias (128x136)
    short* As = SH;
    short* Bs = SH + 4096;
    int tx = blockIdx.x;
    int h0 = (tx >> 4) * 8;
    int w0 = (tx & 15) * 16;
    int m0 = blockIdx.y * 128;
    int b  = blockIdx.z;
    const short* Bz = Bt + (size_t)b * HW * DIM;
    int tid = threadIdx.x;
    int lane = tid & 63, w = tid >> 6;
    int wr = w >> 1, wc = w & 1;
    int lm = lane & 15, quad = lane >> 4;

    f32x4 acc[4][4];
#pragma unroll
    for (int i = 0; i < 4; ++i)
#pragma unroll
        for (int j = 0; j < 4; ++j) acc[i][j] = 0.f;

    int srow = tid >> 2, sseg = tid & 3;
    int pu = srow >> 3, pv = srow & 7;
    int p1 = ((h0 + pu) << 8) + w0 + pv;       // pat 0
    int p2 = p1 + 8;                           // pat 1
    for (int k0 = 0; k0 < DIM; k0 += 32) {
        gl_lds16(A + (size_t)(m0 + srow) * DIM + k0 + sseg * 8, As + tid * 8);
        gl_lds16(A + (size_t)(m0 + 64 + srow) * DIM + k0 + sseg * 8, As + (tid + 256) * 8);
        gl_lds16(Bz + (size_t)p1 * DIM + k0 + sseg * 8, Bs + tid * 8);
        gl_lds16(Bz + (size_t)p2 * DIM + k0 + sseg * 8, Bs + (tid + 256) * 8);
        __syncthreads();
        bf16x8 af[4], bfr[4];
#pragma unroll
        for (int i = 0; i < 4; ++i)
            af[i] = __builtin_bit_cast(bf16x8, *(const s16x8*)&As[(wr * 64 + i * 16 + lm) * 32 + quad * 8]);
#pragma unroll
        for (int j = 0; j < 4; ++j)
            bfr[j] = __builtin_bit_cast(bf16x8, *(const s16x8*)&Bs[(wc * 64 + j * 16 + lm) * 32 + quad * 8]);
#pragma unroll
        for (int i = 0; i < 4; ++i)
#pragma unroll
            for (int j = 0; j < 4; ++j)
                acc[i][j] = __builtin_amdgcn_mfma_f32_16x16x32_bf16(af[i], bfr[j], acc[i][j], 0, 0, 0);
        __syncthreads();
    }
    // dump acc (bf16) into Ep (aliases As/Bs — safe after the loop's final barrier)
#pragma unroll
    for (int i = 0; i < 4; ++i)
#pragma unroll
        for (int j = 0; j < 4; ++j)
#pragma unroll
            for (int r = 0; r < 4; ++r)
                SH[(wr * 64 + i * 16 + quad * 4 + r) * 136 + wc * 64 + j * 16 + lm] =
                    f2b(acc[i][j][r]);
    __syncthreads();
    // vector write-out: E[(b*HID + m0+row)<<16 | tx*128 + n]
#pragma unroll
    for (int kq = 0; kq < 8; ++kq) {
        int idx = kq * 256 + tid;
        int row = idx >> 4, seg = idx & 15;
        s16x8 vv = *(const s16x8*)&SH[row * 136 + seg * 8];
        *(s16x8*)&E[(((size_t)(b * HID + m0 + row)) << 16) + tx * 128 + seg * 8] = vv;
    }
}

// ---------------------------------------------------------------------------
// Circular conv as per-channel MFMA GEMM: T[uv,p] = M_c[uv,k] * E[p,k].
// M_c (64x64) built in LDS from the 64 taps. K-dim XOR-swizzled (k-block ^ row&7).
// ---------------------------------------------------------------------------
__global__ __launch_bounds__(256) void k_circ(const short* __restrict__ E,
                                              const float* __restrict__ Kt,
                                              short* __restrict__ T) {
    __shared__ __align__(16) short SH[4096 + 8704];  // Ms 64x64 | Bs 128x64 (alias Cs 64x136)
    short* Ms = SH;
    short* Bs = SH + 4096;
    short* Cs = SH + 4096;
    int pt = blockIdx.x;                 // patch tile (128 patches)
    int c  = blockIdx.y;
    int b  = blockIdx.z;
    int tid = threadIdx.x;
    int lane = tid & 63, wn = tid >> 6;
    int lm = lane & 15, quad = lane >> 4;

    // build M_c: M[uv][k] = kt[(ku-u)&7][(kv-v)&7], swizzled k-block
    const float* Kc = Kt + c * 64;
#pragma unroll
    for (int e = 0; e < 16; ++e) {
        int idx = tid * 16 + e;
        int uv = idx >> 6, k = idx & 63;
        int a = ((k >> 3) - (uv >> 3)) & 7;
        int bb = ((k & 7) - (uv & 7)) & 7;
        Ms[uv * 64 + ((((k >> 3) ^ (uv & 7))) << 3) + (k & 7)] = f2b(Kc[a * 8 + bb]);
    }
    // stage B: 128 patches x 64 uv, source pre-swizzled so LDS-linear = swizzled layout
    const short* Eblk = E + (((size_t)(b * HID + c)) << 16) + pt * 8192;
#pragma unroll
    for (int ps = 0; ps < 4; ++ps)
        gl_lds16(Eblk + ps * 2048 + (tid >> 3) * 64 + (((tid & 7) ^ ((tid >> 3) & 7)) << 3),
                 Bs + ps * 2048 + tid * 8);
    __syncthreads();

    f32x4 acc[4][2];
#pragma unroll
    for (int i = 0; i < 4; ++i) { acc[i][0] = 0.f; acc[i][1] = 0.f; }
#pragma unroll
    for (int ks = 0; ks < 2; ++ks) {
        bf16x8 af[4], bfr[2];
#pragma unroll
        for (int i = 0; i < 4; ++i)
            af[i] = __builtin_bit_cast(bf16x8,
                *(const s16x8*)&Ms[(i * 16 + lm) * 64 + (((ks * 4 + quad) ^ (lm & 7)) << 3)]);
#pragma unroll
        for (int j = 0; j < 2; ++j)
            bfr[j] = __builtin_bit_cast(bf16x8,
                *(const s16x8*)&Bs[(wn * 32 + j * 16 + lm) * 64 + (((ks * 4 + quad) ^ (lm & 7)) << 3)]);
#pragma unroll
        for (int i = 0; i < 4; ++i)
#pragma unroll
            for (int j = 0; j < 2; ++j)
                acc[i][j] = __builtin_amdgcn_mfma_f32_16x16x32_bf16(af[i], bfr[j], acc[i][j], 0, 0, 0);
    }
    __syncthreads();   // Bs dead; Cs may alias
#pragma unroll
    for (int i = 0; i < 4; ++i)
#pragma unroll
        for (int j = 0; j < 2; ++j)
#pragma unroll
            for (int r = 0; r < 4; ++r)
                Cs[(i * 16 + quad * 4 + r) * 136 + wn * 32 + j * 16 + lm] = f2b(acc[i][j][r]);
    __syncthreads();
    // pack to spatial T: row (ph*8+u), 8 w-contiguous bf16 per patch
    short* Tc = T + (((size_t)(b * HID + c)) << 16);
#pragma unroll
    for (int kq = 0; kq < 4; ++kq) {
        int idx = kq * 256 + tid;
        int u = idx >> 7, pl = idx & 127;
        int pid = pt * 128 + pl;
        s16x8 ov;
#pragma unroll
        for (int v = 0; v < 8; ++v) ov[v] = Cs[(u * 8 + v) * 136 + pl];
        *(s16x8*)&Tc[(size_t)((((pid >> 5) * 8 + u) << 8) + ((pid & 31) << 3))] = ov;
    }
}

// ---------------------------------------------------------------------------
// depthwise 3x3 + gelu-gate on bf16 T -> G bf16 [b][c<192][hw]
// ---------------------------------------------------------------------------
__global__ __launch_bounds__(256) void k_dwgate(const short* __restrict__ Y,
                                                const float* __restrict__ Wdw,
                                                short* __restrict__ G) {
    int bz = blockIdx.z;
    int b = bz / 192;
    int c = bz % 192;
    int h0 = blockIdx.y * 32, w0 = blockIdx.x * 32;
    __shared__ float s1[34 * 34];
    __shared__ float s2[34 * 34];
    const short* Y1 = Y + ((size_t)(b * HID + c) << 16);
    const short* Y2 = Y + ((size_t)(b * HID + c + 192) << 16);
    int tid = threadIdx.x;
    for (int i = tid; i < 34 * 34; i += 256) {
        int r = i / 34, cl = i % 34;
        int gh = h0 + r - 1, gw = w0 + cl - 1;
        bool ok = (gh >= 0 && gh < 256 && gw >= 0 && gw < 256);
        float v1 = 0.f, v2 = 0.f;
        if (ok) {
            size_t off = (size_t)gh * 256 + gw;
            v1 = b2f(Y1[off]);
            v2 = b2f(Y2[off]);
        }
        s1[i] = v1;
        s2[i] = v2;
    }
    float wa[9], wb[9];
#pragma unroll
    for (int j = 0; j < 9; ++j) {
        wa[j] = Wdw[c * 9 + j];
        wb[j] = Wdw[(c + 192) * 9 + j];
    }
    __syncthreads();
    short* Gc = G + ((size_t)(b * 192 + c) << 16);
#pragma unroll
    for (int kq = 0; kq < 4; ++kq) {
        int idx = tid + kq * 256;
        int r = idx >> 5, cl = idx & 31;
        float z1 = 0.f, z2 = 0.f;
#pragma unroll
        for (int i = 0; i < 3; ++i)
#pragma unroll
            for (int j = 0; j < 3; ++j) {
                z1 += s1[(r + i) * 34 + cl + j] * wa[i * 3 + j];
                z2 += s2[(r + i) * 34 + cl + j] * wb[i * 3 + j];
            }
        float ge = 0.5f * z1 * (1.f + erff(z1 * 0.70710678118654752f));
        Gc[(size_t)(h0 + r) * 256 + w0 + cl] = f2b(ge * z2);
    }
}

// ---------------------------------------------------------------------------
// G [b][c<192][hw] bf16 -> Gt [b][hw][192] bf16 (same XOR-swizzled transpose)
// ---------------------------------------------------------------------------
__global__ __launch_bounds__(256) void k_transG(const short* __restrict__ G, short* __restrict__ Gt) {
    int hw0 = blockIdx.x * 64, c0 = blockIdx.y * 64, b = blockIdx.z;
    __shared__ __align__(16) short S[64 * 64];
    int t = threadIdx.x;
    const short* Gb = G + ((size_t)(b * 192) << 16);
    short* Gtb = Gt + (size_t)b * HW * 192;
#pragma unroll
    for (int p = 0; p < 2; ++p) {
        int row = p * 32 + (t >> 3), sb = t & 7;
        s16x8 v = *(const s16x8*)&Gb[((size_t)(c0 + row) << 16) + hw0 + sb * 8];
        *(s16x8*)&S[row * 64 + ((sb ^ (row >> 3)) << 3)] = v;
    }
    __syncthreads();
#pragma unroll
    for (int p = 0; p < 2; ++p) {
        int row = p * 32 + (t >> 3), ch = t & 7;
        s16x8 v;
#pragma unroll
        for (int j = 0; j < 8; ++j)
            v[j] = S[(ch * 8 + j) * 64 + (row ^ (ch << 3))];
        *(s16x8*)&Gtb[(size_t)(hw0 + row) * 192 + c0 + ch * 8] = v;
    }
}

// ---------------------------------------------------------------------------
// MFMA bf16 GEMM (GEMM2): C[z][m][n] = sum_k A[m][k] * Bt[z][n][k], C fp32
// ---------------------------------------------------------------------------
__global__ __launch_bounds__(256) void k_gemm_bf16(const short* __restrict__ A,
                                                   const short* __restrict__ Bt,
                                                   float* __restrict__ C,
                                                   int N, int K) {
    __shared__ __align__(16) short As[128 * 32];
    __shared__ __align__(16) short Bs[128 * 32];
    const short* Bz = Bt + (size_t)blockIdx.z * (size_t)N * K;
    float* Cz = C + (size_t)blockIdx.z * (size_t)384 * N;
    int n0 = blockIdx.x * 128, m0 = blockIdx.y * 128;
    int tid = threadIdx.x;
    int lane = tid & 63, w = tid >> 6;
    int wr = w >> 1, wc = w & 1;
    int lm = lane & 15, quad = lane >> 4;

    f32x4 acc[4][4];
#pragma unroll
    for (int i = 0; i < 4; ++i)
#pragma unroll
        for (int j = 0; j < 4; ++j) acc[i][j] = 0.f;

    int srow = tid >> 2, sseg = tid & 3;
    for (int k0 = 0; k0 < K; k0 += 32) {
        gl_lds16(A + (size_t)(m0 + srow) * K + k0 + sseg * 8, As + tid * 8);
        gl_lds16(A + (size_t)(m0 + 64 + srow) * K + k0 + sseg * 8, As + (tid + 256) * 8);
        gl_lds16(Bz + (size_t)(n0 + srow) * K + k0 + sseg * 8, Bs + tid * 8);
        gl_lds16(Bz + (size_t)(n0 + 64 + srow) * K + k0 + sseg * 8, Bs + (tid + 256) * 8);
        __syncthreads();
        bf16x8 af[4], bfr[4];
#pragma unroll
        for (int i = 0; i < 4; ++i)
            af[i] = __builtin_bit_cast(bf16x8, *(const s16x8*)&As[(wr * 64 + i * 16 + lm) * 32 + quad * 8]);
#pragma unroll
        for (int j = 0; j < 4; ++j)
            bfr[j] = __builtin_bit_cast(bf16x8, *(const s16x8*)&Bs[(wc * 64 + j * 16 + lm) * 32 + quad * 8]);
#pragma unroll
        for (int i = 0; i < 4; ++i)
#pragma unroll
            for (int j = 0; j < 4; ++j)
                acc[i][j] = __builtin_amdgcn_mfma_f32_16x16x32_bf16(af[i], bfr[j], acc[i][j], 0, 0, 0);
        __syncthreads();
    }
#pragma unroll
    for (int i = 0; i < 4; ++i) {
        int r0 = m0 + wr * 64 + i * 16 + quad * 4;
#pragma unroll
        for (int j = 0; j < 4; ++j) {
            int cidx = n0 + wc * 64 + j * 16 + lm;
#pragma unroll
            for (int r = 0; r < 4; ++r)
                Cz[(size_t)(r0 + r) * N + cidx] = acc[i][j][r];
        }
    }
}

// ---------------------------------------------------------------------------
extern "C" void kernel_launch(void* const* d_in, const int* in_sizes, int n_in,
                              void* d_out, int out_size, void* d_ws, size_t ws_size,
                              hipStream_t stream) {
    const float* x     = (const float*)d_in[0];
    const float* ff    = (const float*)d_in[1];
    const float* w_in  = (const float*)d_in[2];
    const float* w_dw  = (const float*)d_in[3];
    const float* w_out = (const float*)d_in[4];
    float* out = (float*)d_out;

    char* ws = (char*)d_ws;
    float* Kbuf = (float*)ws;                                    // 98304 B
    short* wbin = (short*)(ws + 98304);                          // 294912 B
    short* wbout = (short*)(ws + 393216);                        // 147456 B
    short* bufA = (short*)(ws + 540672);                         // 100663296 B: xbT, then T
    short* bufB = (short*)(ws + 540672 + (size_t)100663296);     // 100663296 B: E, then G/Gt
    short* G  = bufB;
    short* Gt = (short*)((char*)bufB + (size_t)50331648);

    k_precompute<<<384, 64, 0, stream>>>(ff, Kbuf);
    k_cvtw<<<(DIM * DIM + 255) / 256, 256, 0, stream>>>(w_in, wbin, DIM * DIM);
    k_cvtw<<<(DIM * 192 + 255) / 256, 256, 0, stream>>>(w_out, wbout, DIM * 192);
    k_cvtx<<<dim3(HW / 64, DIM / 64, BB), 256, 0, stream>>>(x, bufA);

    // pure GEMM1 -> E bf16 patch-major [b][c][patch][uv]
    k_gemm1_patch<<<dim3(512, 3, BB), 256, 0, stream>>>(wbin, bufA, bufB);

    // circular conv as per-channel 64x64 MFMA GEMM -> T bf16 spatial (reuses bufA)
    k_circ<<<dim3(8, 384, BB), 256, 0, stream>>>(bufB, Kbuf, bufA);

    // depthwise 3x3 + gelu-gate -> G bf16 (reuses bufB; E is dead)
    k_dwgate<<<dim3(8, 8, BB * 192), 256, 0, stream>>>(bufA, w_dw, G);

    // transpose G -> Gt [hw][192]
    k_transG<<<dim3(HW / 64, 3, BB), 256, 0, stream>>>(G, Gt);

    // GEMM2: out = w_out @ g  (M=384, N=65536/batch, K=192)
    k_gemm_bf16<<<dim3(HW / 128, 3, BB), 256, 0, stream>>>(wbout, Gt, out, HW, 192);
}